// Round 9
// baseline (192.210 us; speedup 1.0000x reference)
//
#include <hip/hip_runtime.h>
#include <hip/hip_bf16.h>

typedef __hip_bfloat16 bf16;
typedef __attribute__((ext_vector_type(8))) short sh8;
typedef __attribute__((ext_vector_type(4))) float f32x4;

// Problem constants
#define BB 2
#define TT 2048
#define EE 1024
#define NH 16
#define HD 64
#define M_ROWS (BB * TT)          // 4096
#define PPAD 72                   // P-tile LDS row stride (elements)

__device__ __forceinline__ float b2f(bf16 v) { return __bfloat162float(v); }
__device__ __forceinline__ bf16 f2b(float v) { return __float2bfloat16(v); }
__device__ __forceinline__ unsigned short f2bu(float v) {
    union { bf16 b; unsigned short u; } x; x.b = f2b(v); return x.u;
}

// async global->LDS, 16B per lane: LDS gets (firstlane base) + lane*16.
__device__ __forceinline__ void gl2lds16(const bf16* g, bf16* l) {
    __builtin_amdgcn_global_load_lds(
        (__attribute__((address_space(1))) void*)g,
        (__attribute__((address_space(3))) void*)l, 16, 0, 0);
}

// ---------------------------------------------------------------------------
// Prep 1: cast x (f32) -> bf16, 4 elems/thread
// ---------------------------------------------------------------------------
__global__ __launch_bounds__(256) void cast_x(
    const float* __restrict__ in, bf16* __restrict__ outb) {
    const int i = blockIdx.x * 256 + threadIdx.x;
    const float4 v = ((const float4*)in)[i];
    ushort4 u;
    u.x = f2bu(v.x); u.y = f2bu(v.y); u.z = f2bu(v.z); u.w = f2bu(v.w);
    ((ushort4*)outb)[i] = u;
}

// ---------------------------------------------------------------------------
// Prep 2: transpose-cast weights [K,N] f32 -> [N,K] bf16 (64x64 LDS tiles).
// ---------------------------------------------------------------------------
__global__ __launch_bounds__(256) void transpose_cast(
    const float* __restrict__ Wq, bf16* __restrict__ Wqt,
    const float* __restrict__ Wp, bf16* __restrict__ Wpt) {
    __shared__ float Ld[64][65];
    const float* src; bf16* dst; int ncols;
    if (blockIdx.z == 0) { src = Wq; dst = Wqt; ncols = 3072; }
    else {
        if (blockIdx.x >= 16) return;
        src = Wp; dst = Wpt; ncols = 1024;
    }
    const int nc0 = blockIdx.x * 64, kr0 = blockIdx.y * 64;
#pragma unroll
    for (int i = 0; i < 16; ++i) {
        const int e = threadIdx.x + i * 256;
        Ld[e >> 6][e & 63] = src[(size_t)(kr0 + (e >> 6)) * ncols + nc0 + (e & 63)];
    }
    __syncthreads();
#pragma unroll
    for (int i = 0; i < 16; ++i) {
        const int e = threadIdx.x + i * 256;
        const int r2 = e & 63, c2 = e >> 6;
        dst[(size_t)(nc0 + c2) * EE + kr0 + r2] = f2b(Ld[r2][c2]);
    }
}

// ---------------------------------------------------------------------------
// MFMA GEMM core: C[128x128] = A[M,1024] @ Bt[N,1024]^T, bf16 in, f32 accum.
// ---------------------------------------------------------------------------
__device__ __forceinline__ void mfma_gemm_core(
    const bf16* __restrict__ A, const bf16* __restrict__ Bt,
    int m0, int n0, f32x4 acc[4][4], bf16* Al, bf16* Bl) {
    const int tid = threadIdx.x, w = tid >> 6, lane = tid & 63;
    const int li = lane & 15, quad = lane >> 4;
    const int wm = (w & 1) * 64, wn = (w >> 1) * 64;
    const int srow = w * 32 + (lane >> 3);
    const int scol = (lane & 7) * 8;

#pragma unroll
    for (int mt = 0; mt < 4; ++mt)
#pragma unroll
        for (int nt = 0; nt < 4; ++nt) acc[mt][nt] = (f32x4){0.f, 0.f, 0.f, 0.f};

    for (int k0 = 0; k0 < EE; k0 += 64) {
        __syncthreads();
#pragma unroll
        for (int j = 0; j < 4; ++j) {
            const int row = srow + j * 8;
            const int sk = scol ^ ((row & 7) * 8);
            gl2lds16(A  + (size_t)(m0 + row) * EE + k0 + sk, Al + row * 64 + scol);
            gl2lds16(Bt + (size_t)(n0 + row) * EE + k0 + sk, Bl + row * 64 + scol);
        }
        __syncthreads();
#pragma unroll
        for (int ks = 0; ks < 2; ++ks) {
            const int kof = (ks * 32 + quad * 8) ^ ((li & 7) * 8);
            sh8 af[4], bv[4];
#pragma unroll
            for (int mt = 0; mt < 4; ++mt)
                af[mt] = *(const sh8*)(Al + (wm + mt * 16 + li) * 64 + kof);
#pragma unroll
            for (int nt = 0; nt < 4; ++nt)
                bv[nt] = *(const sh8*)(Bl + (wn + nt * 16 + li) * 64 + kof);
#pragma unroll
            for (int mt = 0; mt < 4; ++mt)
#pragma unroll
                for (int nt = 0; nt < 4; ++nt)
                    acc[mt][nt] = __builtin_amdgcn_mfma_f32_16x16x32_bf16(
                        af[mt], bv[nt], acc[mt][nt], 0, 0, 0);
        }
    }
}

// ---------------------------------------------------------------------------
// QKV GEMM (MFMA). Q is PRE-SCALED by 0.125 (folded attention scale).
// ---------------------------------------------------------------------------
__global__ __launch_bounds__(256) void gemm_qkv_mfma(
    const bf16* __restrict__ A, const bf16* __restrict__ Bt,
    const float* __restrict__ bias,
    bf16* __restrict__ Qb, bf16* __restrict__ Kb, bf16* __restrict__ Vb) {
    __shared__ bf16 Al[128 * 64];
    __shared__ bf16 Bl[128 * 64];
    f32x4 acc[4][4];
    const int m0 = blockIdx.y * 128, n0 = blockIdx.x * 128;
    mfma_gemm_core(A, Bt, m0, n0, acc, Al, Bl);

    const int tid = threadIdx.x, w = tid >> 6, lane = tid & 63;
    const int li = lane & 15, quad = lane >> 4;
    const int wm = (w & 1) * 64, wn = (w >> 1) * 64;
    const int which = n0 >> 10;

#pragma unroll
    for (int nt = 0; nt < 4; ++nt) {
        const int n = n0 + wn + nt * 16 + li;
        const int hseg = n & 1023;
        const int h = hseg >> 6, d = hseg & 63;
        const float bv = bias[n];
        if (which == 2) {
#pragma unroll
            for (int mt = 0; mt < 4; ++mt) {
                const int mb = m0 + wm + mt * 16 + quad * 4;
                const int b = mb >> 11, t = mb & (TT - 1);
                ushort4 u;
                u.x = f2bu(acc[mt][nt][0] + bv);
                u.y = f2bu(acc[mt][nt][1] + bv);
                u.z = f2bu(acc[mt][nt][2] + bv);
                u.w = f2bu(acc[mt][nt][3] + bv);
                *(ushort4*)(Vb + ((size_t)((b * NH + h) * HD + d)) * TT + t) = u;
            }
        } else {
            bf16* dst = (which == 0) ? Qb : Kb;
            const float scl = (which == 0) ? 0.125f : 1.0f;
#pragma unroll
            for (int mt = 0; mt < 4; ++mt)
#pragma unroll
                for (int r = 0; r < 4; ++r) {
                    const int m = m0 + wm + mt * 16 + quad * 4 + r;
                    const int b = m >> 11, t = m & (TT - 1);
                    dst[((size_t)(b * NH + h) * TT + t) * HD + d] =
                        f2b((acc[mt][nt][r] + bv) * scl);
                }
        }
    }
}

// ---------------------------------------------------------------------------
// Output projection (MFMA) -> f32 out.
// ---------------------------------------------------------------------------
__global__ __launch_bounds__(256) void gemm_proj_mfma(
    const bf16* __restrict__ A, const bf16* __restrict__ Bt,
    const float* __restrict__ bias, float* __restrict__ C) {
    __shared__ bf16 Al[128 * 64];
    __shared__ bf16 Bl[128 * 64];
    f32x4 acc[4][4];
    const int m0 = blockIdx.y * 128, n0 = blockIdx.x * 128;
    mfma_gemm_core(A, Bt, m0, n0, acc, Al, Bl);

    const int tid = threadIdx.x, w = tid >> 6, lane = tid & 63;
    const int li = lane & 15, quad = lane >> 4;
    const int wm = (w & 1) * 64, wn = (w >> 1) * 64;

#pragma unroll
    for (int nt = 0; nt < 4; ++nt) {
        const int n = n0 + wn + nt * 16 + li;
        const float bv = bias[n];
#pragma unroll
        for (int mt = 0; mt < 4; ++mt)
#pragma unroll
            for (int r = 0; r < 4; ++r) {
                const int m = m0 + wm + mt * 16 + quad * 4 + r;
                C[(size_t)m * EE + n] = acc[mt][nt][r] + bv;
            }
    }
}

// ---------------------------------------------------------------------------
// MFMA flash attention v4: 128-q blocks, 8 waves (512 thr). Each wave keeps
// the v3 16-q x 64-key chain (S^T=K Q^T swap, exp without shift, b64 P
// writes, scalar per-lane l). K/V staging+barriers amortized over 2x q rows;
// waves below the diagonal skip compute on the final tile only.
// Q pre-scaled by 0.125. Q,K:[B,H,T,64]; V:[B,H,64,T]; Y:[B,T,E] bf16.
// ---------------------------------------------------------------------------
__global__ __launch_bounds__(512) void attn_mfma(
    const bf16* __restrict__ Q, const bf16* __restrict__ K,
    const bf16* __restrict__ Vt, bf16* __restrict__ Y) {
    __shared__ bf16 Kl[2][64 * 64];
    __shared__ bf16 Vl[2][64 * 64];
    __shared__ bf16 Pl[8][16 * PPAD];   // per-wave, layout [q=li][key]

    const int tid  = threadIdx.x;
    const int w    = tid >> 6;          // 0..7
    const int lane = tid & 63;
    const int li   = lane & 15;
    const int quad = lane >> 4;
    const int swz  = (li & 7) * 8;
    // global LPT: longest chunks (c=15) dispatch first
    const int idx  = blockIdx.x;
    const int c    = 15 - (idx >> 5);   // q-chunk 0..15 (128 rows each)
    const int bh   = idx & 31;
    const int q0   = c << 7;
    const int qw0  = q0 + w * 16;       // this wave's first q row

    const bf16* Qb = Q  + (size_t)bh * TT * HD;
    const bf16* Kb = K  + (size_t)bh * TT * HD;
    const bf16* Vb = Vt + (size_t)bh * HD * TT;

    // Q fragments (B-operand; layout same as A), pre-scaled
    sh8 qf0 = *(const sh8*)(Qb + (size_t)(qw0 + li) * HD + quad * 8);
    sh8 qf1 = *(const sh8*)(Qb + (size_t)(qw0 + li) * HD + 32 + quad * 8);

    f32x4 o[4];
#pragma unroll
    for (int nt = 0; nt < 4; ++nt) o[nt] = (f32x4){0.f, 0.f, 0.f, 0.f};
    float lacc = 0.f;                    // partial l for q = qw0 + li

    const int l8 = lane >> 3, l7 = lane & 7;
    const int gcol = ((l7 ^ l8) * 8);    // swizzled source column
    const int srow = w * 8 + l8;         // staging row: 8 rows per wave

    const int ntiles = 2 * c + 2;
    const int itd    = 2 * c + (w >> 2); // this wave's diagonal tile
    // prologue: stage tile 0 into buffer 0 (1 K + 1 V instr per lane)
    gl2lds16(Kb + (size_t)srow * HD + gcol, &Kl[0][srow * 64]);
    gl2lds16(Vb + (size_t)srow * TT + gcol, &Vl[0][srow * 64]);

    for (int it = 0; it < ntiles; ++it) {
        const int cur = it & 1;
        __syncthreads();                 // drains loads for tile `it`
        if (it + 1 < ntiles) {           // prefetch tile it+1 (overlaps compute)
            const int j1 = (it + 1) << 6;
            const int nxt = cur ^ 1;
            gl2lds16(Kb + (size_t)(j1 + srow) * HD + gcol, &Kl[nxt][srow * 64]);
            gl2lds16(Vb + (size_t)srow * TT + j1 + gcol, &Vl[nxt][srow * 64]);
        }
        if (it > itd) continue;          // this wave fully below diagonal
        const bf16* kb = &Kl[cur][0];
        const bf16* vb = &Vl[cur][0];
        const int j0 = it << 6;

        // ---- S^T = K Q^T: row = key (quad*4+r in tile nt), col = q (li) ----
        const bool diag = (it == itd);
#pragma unroll
        for (int nt = 0; nt < 4; ++nt) {
            f32x4 a = (f32x4){0.f, 0.f, 0.f, 0.f};
            sh8 kf0 = *(const sh8*)(kb + (nt * 16 + li) * 64 + ((quad * 8) ^ swz));
            a = __builtin_amdgcn_mfma_f32_16x16x32_bf16(kf0, qf0, a, 0, 0, 0);
            sh8 kf1 = *(const sh8*)(kb + (nt * 16 + li) * 64 + ((32 + quad * 8) ^ swz));
            a = __builtin_amdgcn_mfma_f32_16x16x32_bf16(kf1, qf1, a, 0, 0, 0);

            ushort4 u;
            float p0, p1, p2, p3;
            if (diag) {
                const int keyb = j0 + nt * 16 + quad * 4;
                const int qg = qw0 + li;
                p0 = (keyb + 0 > qg) ? 0.f : __expf(a[0]);
                p1 = (keyb + 1 > qg) ? 0.f : __expf(a[1]);
                p2 = (keyb + 2 > qg) ? 0.f : __expf(a[2]);
                p3 = (keyb + 3 > qg) ? 0.f : __expf(a[3]);
            } else {
                p0 = __expf(a[0]); p1 = __expf(a[1]);
                p2 = __expf(a[2]); p3 = __expf(a[3]);
            }
            lacc += (p0 + p1) + (p2 + p3);
            u.x = f2bu(p0); u.y = f2bu(p1); u.z = f2bu(p2); u.w = f2bu(p3);
            *(ushort4*)(&Pl[w][li * PPAD + nt * 16 + quad * 4]) = u;
        }

        // ---- O += P V  (A = P[q=li][key] via ds_read_b128) ----
#pragma unroll
        for (int ks = 0; ks < 2; ++ks) {
            sh8 pf = *(const sh8*)(&Pl[w][li * PPAD + ks * 32 + quad * 8]);
#pragma unroll
            for (int nt = 0; nt < 4; ++nt) {
                sh8 vf = *(const sh8*)(vb + (nt * 16 + li) * 64 +
                                       ((ks * 32 + quad * 8) ^ swz));
                o[nt] = __builtin_amdgcn_mfma_f32_16x16x32_bf16(pf, vf, o[nt], 0, 0, 0);
            }
        }
    }

    // ---- l reduction: sum the 4 quad-lanes sharing this li ----
    lacc += __shfl_xor(lacc, 16, 64);
    lacc += __shfl_xor(lacc, 32, 64);
    float rinv[4];
#pragma unroll
    for (int r = 0; r < 4; ++r)
        rinv[r] = 1.0f / __shfl(lacc, quad * 4 + r, 64);

    const int b = bh >> 4, h = bh & 15;
#pragma unroll
    for (int nt = 0; nt < 4; ++nt)
#pragma unroll
        for (int r = 0; r < 4; ++r) {
            const int q = qw0 + quad * 4 + r;
            Y[((size_t)(b * TT + q)) * EE + h * HD + nt * 16 + li] =
                f2b(o[nt][r] * rinv[r]);
        }
}

// ---------------------------------------------------------------------------
extern "C" void kernel_launch(void* const* d_in, const int* in_sizes, int n_in,
                              void* d_out, int out_size, void* d_ws, size_t ws_size,
                              hipStream_t stream) {
    const float* x      = (const float*)d_in[0];
    const float* w_qkv  = (const float*)d_in[1];
    const float* b_qkv  = (const float*)d_in[2];
    const float* w_proj = (const float*)d_in[3];
    const float* b_proj = (const float*)d_in[4];
    float* out = (float*)d_out;

    const size_t SZ = (size_t)M_ROWS * EE;
    bf16* Q   = (bf16*)d_ws;
    bf16* K   = Q + SZ;
    bf16* V   = K + SZ;
    bf16* XB  = V + SZ;            // x cast; later reused as Y
    bf16* WQT = XB + SZ;           // [3072,1024]
    bf16* WPT = WQT + 3 * SZ / 4;  // [1024,1024]
    bf16* Y   = XB;                // alias: XB dead after gemm_qkv

    cast_x<<<dim3(M_ROWS * EE / 1024), dim3(256), 0, stream>>>(x, XB);
    transpose_cast<<<dim3(48, 16, 2), dim3(256), 0, stream>>>(w_qkv, WQT, w_proj, WPT);

    gemm_qkv_mfma<<<dim3(24, 32), dim3(256), 0, stream>>>(XB, WQT, b_qkv, Q, K, V);

    // 128-q chunks x 32 bh = 512 blocks of 512 threads
    attn_mfma<<<dim3((TT / 128) * (BB * NH)), dim3(512), 0, stream>>>(Q, K, V, Y);

    gemm_proj_mfma<<<dim3(8, 32), dim3(256), 0, stream>>>(Y, WPT, b_proj, out);
}

// Round 10
// 185.386 us; speedup vs baseline: 1.0368x; 1.0368x over previous
//
#include <hip/hip_runtime.h>
#include <hip/hip_bf16.h>

typedef __hip_bfloat16 bf16;
typedef __attribute__((ext_vector_type(8))) short sh8;
typedef __attribute__((ext_vector_type(4))) float f32x4;

// Problem constants
#define BB 2
#define TT 2048
#define EE 1024
#define NH 16
#define HD 64
#define M_ROWS (BB * TT)          // 4096
#define PPAD 72                   // P-tile LDS row stride (elements)

__device__ __forceinline__ float b2f(bf16 v) { return __bfloat162float(v); }
__device__ __forceinline__ bf16 f2b(float v) { return __float2bfloat16(v); }
__device__ __forceinline__ unsigned short f2bu(float v) {
    union { bf16 b; unsigned short u; } x; x.b = f2b(v); return x.u;
}

// async global->LDS, 16B per lane: LDS gets (firstlane base) + lane*16.
__device__ __forceinline__ void gl2lds16(const bf16* g, bf16* l) {
    __builtin_amdgcn_global_load_lds(
        (__attribute__((address_space(1))) void*)g,
        (__attribute__((address_space(3))) void*)l, 16, 0, 0);
}

// ---------------------------------------------------------------------------
// Merged prep: block ranges
//   [0, 4096)        cast x (f32->bf16), 4 elems/thread
//   [4096, 4864)     transpose-cast w_qkv  [1024,3072] -> [3072,1024] bf16
//   [4864, 5120)     transpose-cast w_proj [1024,1024] -> [1024,1024] bf16
// ---------------------------------------------------------------------------
__global__ __launch_bounds__(256) void prep(
    const float* __restrict__ x, bf16* __restrict__ xb,
    const float* __restrict__ Wq, bf16* __restrict__ Wqt,
    const float* __restrict__ Wp, bf16* __restrict__ Wpt) {
    const int bid = blockIdx.x;
    if (bid < 4096) {
        const int i = bid * 256 + threadIdx.x;
        const float4 v = ((const float4*)x)[i];
        ushort4 u;
        u.x = f2bu(v.x); u.y = f2bu(v.y); u.z = f2bu(v.z); u.w = f2bu(v.w);
        ((ushort4*)xb)[i] = u;
        return;
    }
    __shared__ float Ld[64][65];
    const float* src; bf16* dst; int ncols, nc0, kr0;
    if (bid < 4096 + 768) {
        const int t = bid - 4096;
        src = Wq; dst = Wqt; ncols = 3072;
        nc0 = (t % 48) * 64; kr0 = (t / 48) * 64;
    } else {
        const int t = bid - 4096 - 768;
        src = Wp; dst = Wpt; ncols = 1024;
        nc0 = (t % 16) * 64; kr0 = (t / 16) * 64;
    }
#pragma unroll
    for (int i = 0; i < 16; ++i) {
        const int e = threadIdx.x + i * 256;
        Ld[e >> 6][e & 63] = src[(size_t)(kr0 + (e >> 6)) * ncols + nc0 + (e & 63)];
    }
    __syncthreads();
#pragma unroll
    for (int i = 0; i < 16; ++i) {
        const int e = threadIdx.x + i * 256;
        const int r2 = e & 63, c2 = e >> 6;
        dst[(size_t)(nc0 + c2) * EE + kr0 + r2] = f2b(Ld[r2][c2]);
    }
}

// ---------------------------------------------------------------------------
// MFMA GEMM core: C[128x128] = A[M,1024] @ Bt[N,1024]^T, bf16 in, f32 accum.
// ---------------------------------------------------------------------------
__device__ __forceinline__ void mfma_gemm_core(
    const bf16* __restrict__ A, const bf16* __restrict__ Bt,
    int m0, int n0, f32x4 acc[4][4], bf16* Al, bf16* Bl) {
    const int tid = threadIdx.x, w = tid >> 6, lane = tid & 63;
    const int li = lane & 15, quad = lane >> 4;
    const int wm = (w & 1) * 64, wn = (w >> 1) * 64;
    const int srow = w * 32 + (lane >> 3);
    const int scol = (lane & 7) * 8;

#pragma unroll
    for (int mt = 0; mt < 4; ++mt)
#pragma unroll
        for (int nt = 0; nt < 4; ++nt) acc[mt][nt] = (f32x4){0.f, 0.f, 0.f, 0.f};

    for (int k0 = 0; k0 < EE; k0 += 64) {
        __syncthreads();
#pragma unroll
        for (int j = 0; j < 4; ++j) {
            const int row = srow + j * 8;
            const int sk = scol ^ ((row & 7) * 8);
            gl2lds16(A  + (size_t)(m0 + row) * EE + k0 + sk, Al + row * 64 + scol);
            gl2lds16(Bt + (size_t)(n0 + row) * EE + k0 + sk, Bl + row * 64 + scol);
        }
        __syncthreads();
#pragma unroll
        for (int ks = 0; ks < 2; ++ks) {
            const int kof = (ks * 32 + quad * 8) ^ ((li & 7) * 8);
            sh8 af[4], bv[4];
#pragma unroll
            for (int mt = 0; mt < 4; ++mt)
                af[mt] = *(const sh8*)(Al + (wm + mt * 16 + li) * 64 + kof);
#pragma unroll
            for (int nt = 0; nt < 4; ++nt)
                bv[nt] = *(const sh8*)(Bl + (wn + nt * 16 + li) * 64 + kof);
#pragma unroll
            for (int mt = 0; mt < 4; ++mt)
#pragma unroll
                for (int nt = 0; nt < 4; ++nt)
                    acc[mt][nt] = __builtin_amdgcn_mfma_f32_16x16x32_bf16(
                        af[mt], bv[nt], acc[mt][nt], 0, 0, 0);
        }
    }
}

// ---------------------------------------------------------------------------
// QKV GEMM (MFMA). Q is PRE-SCALED by 0.125 (folded attention scale).
// ---------------------------------------------------------------------------
__global__ __launch_bounds__(256) void gemm_qkv_mfma(
    const bf16* __restrict__ A, const bf16* __restrict__ Bt,
    const float* __restrict__ bias,
    bf16* __restrict__ Qb, bf16* __restrict__ Kb, bf16* __restrict__ Vb) {
    __shared__ bf16 Al[128 * 64];
    __shared__ bf16 Bl[128 * 64];
    f32x4 acc[4][4];
    const int m0 = blockIdx.y * 128, n0 = blockIdx.x * 128;
    mfma_gemm_core(A, Bt, m0, n0, acc, Al, Bl);

    const int tid = threadIdx.x, w = tid >> 6, lane = tid & 63;
    const int li = lane & 15, quad = lane >> 4;
    const int wm = (w & 1) * 64, wn = (w >> 1) * 64;
    const int which = n0 >> 10;

#pragma unroll
    for (int nt = 0; nt < 4; ++nt) {
        const int n = n0 + wn + nt * 16 + li;
        const int hseg = n & 1023;
        const int h = hseg >> 6, d = hseg & 63;
        const float bv = bias[n];
        if (which == 2) {
#pragma unroll
            for (int mt = 0; mt < 4; ++mt) {
                const int mb = m0 + wm + mt * 16 + quad * 4;
                const int b = mb >> 11, t = mb & (TT - 1);
                ushort4 u;
                u.x = f2bu(acc[mt][nt][0] + bv);
                u.y = f2bu(acc[mt][nt][1] + bv);
                u.z = f2bu(acc[mt][nt][2] + bv);
                u.w = f2bu(acc[mt][nt][3] + bv);
                *(ushort4*)(Vb + ((size_t)((b * NH + h) * HD + d)) * TT + t) = u;
            }
        } else {
            bf16* dst = (which == 0) ? Qb : Kb;
            const float scl = (which == 0) ? 0.125f : 1.0f;
#pragma unroll
            for (int mt = 0; mt < 4; ++mt)
#pragma unroll
                for (int r = 0; r < 4; ++r) {
                    const int m = m0 + wm + mt * 16 + quad * 4 + r;
                    const int b = m >> 11, t = m & (TT - 1);
                    dst[((size_t)(b * NH + h) * TT + t) * HD + d] =
                        f2b((acc[mt][nt][r] + bv) * scl);
                }
        }
    }
}

// ---------------------------------------------------------------------------
// Output projection (MFMA) -> f32 out.
// ---------------------------------------------------------------------------
__global__ __launch_bounds__(256) void gemm_proj_mfma(
    const bf16* __restrict__ A, const bf16* __restrict__ Bt,
    const float* __restrict__ bias, float* __restrict__ C) {
    __shared__ bf16 Al[128 * 64];
    __shared__ bf16 Bl[128 * 64];
    f32x4 acc[4][4];
    const int m0 = blockIdx.y * 128, n0 = blockIdx.x * 128;
    mfma_gemm_core(A, Bt, m0, n0, acc, Al, Bl);

    const int tid = threadIdx.x, w = tid >> 6, lane = tid & 63;
    const int li = lane & 15, quad = lane >> 4;
    const int wm = (w & 1) * 64, wn = (w >> 1) * 64;

#pragma unroll
    for (int nt = 0; nt < 4; ++nt) {
        const int n = n0 + wn + nt * 16 + li;
        const float bv = bias[n];
#pragma unroll
        for (int mt = 0; mt < 4; ++mt)
#pragma unroll
            for (int r = 0; r < 4; ++r) {
                const int m = m0 + wm + mt * 16 + quad * 4 + r;
                C[(size_t)m * EE + n] = acc[mt][nt][r] + bv;
            }
    }
}

// ---------------------------------------------------------------------------
// MFMA flash attention v3 (round-8 winner): S^T = K Q^T operand swap (P
// writes are 4x ds_write_b64), exp without shift (cancels in O/l), scalar
// per-lane l, async double-buffered K/V staging, global LPT 1-D grid.
// Q pre-scaled by 0.125. Q,K:[B,H,T,64]; V:[B,H,64,T]; Y:[B,T,E] bf16.
// ---------------------------------------------------------------------------
__global__ __launch_bounds__(256) void attn_mfma(
    const bf16* __restrict__ Q, const bf16* __restrict__ K,
    const bf16* __restrict__ Vt, bf16* __restrict__ Y) {
    __shared__ bf16 Kl[2][64 * 64];
    __shared__ bf16 Vl[2][64 * 64];
    __shared__ bf16 Pl[4][16 * PPAD];   // per-wave, layout [q=li][key]

    const int tid  = threadIdx.x;
    const int w    = tid >> 6;
    const int lane = tid & 63;
    const int li   = lane & 15;
    const int quad = lane >> 4;
    const int swz  = (li & 7) * 8;
    // global LPT: all longest blocks (qb=31, every bh) dispatch first
    const int idx  = blockIdx.x;
    const int qb   = 31 - (idx >> 5);
    const int bh   = idx & 31;
    const int q0   = qb << 6;
    const int qw0  = q0 + w * 16;

    const bf16* Qb = Q  + (size_t)bh * TT * HD;
    const bf16* Kb = K  + (size_t)bh * TT * HD;
    const bf16* Vb = Vt + (size_t)bh * HD * TT;

    // Q fragments (B-operand; layout identical to A), pre-scaled
    sh8 qf0 = *(const sh8*)(Qb + (size_t)(qw0 + li) * HD + quad * 8);
    sh8 qf1 = *(const sh8*)(Qb + (size_t)(qw0 + li) * HD + 32 + quad * 8);

    f32x4 o[4];
#pragma unroll
    for (int nt = 0; nt < 4; ++nt) o[nt] = (f32x4){0.f, 0.f, 0.f, 0.f};
    float lacc = 0.f;                    // partial l for q = qw0 + li

    const int l8 = lane >> 3, l7 = lane & 7;
    const int gcol = ((l7 ^ l8) * 8);    // swizzled source column

    const int ntiles = qb + 1;
    // prologue: stage tile 0 into buffer 0
#pragma unroll
    for (int c = 0; c < 2; ++c) {
        const int rb = w * 16 + c * 8;
        gl2lds16(Kb + (size_t)(rb + l8) * HD + gcol, &Kl[0][rb * 64]);
        gl2lds16(Vb + (size_t)(rb + l8) * TT + gcol, &Vl[0][rb * 64]);
    }

    for (int it = 0; it < ntiles; ++it) {
        const int cur = it & 1;
        __syncthreads();                 // drains loads for tile `it`
        if (it + 1 < ntiles) {           // prefetch tile it+1 (overlaps compute)
            const int j1 = (it + 1) << 6;
            const int nxt = cur ^ 1;
#pragma unroll
            for (int c = 0; c < 2; ++c) {
                const int rb = w * 16 + c * 8;
                gl2lds16(Kb + (size_t)(j1 + rb + l8) * HD + gcol, &Kl[nxt][rb * 64]);
                gl2lds16(Vb + (size_t)(rb + l8) * TT + j1 + gcol, &Vl[nxt][rb * 64]);
            }
        }
        const bf16* kb = &Kl[cur][0];
        const bf16* vb = &Vl[cur][0];

        // ---- S^T = K Q^T: row = key (quad*4+r in tile nt), col = q (li) ----
        const bool diag = (it == ntiles - 1);
#pragma unroll
        for (int nt = 0; nt < 4; ++nt) {
            f32x4 a = (f32x4){0.f, 0.f, 0.f, 0.f};
            sh8 kf0 = *(const sh8*)(kb + (nt * 16 + li) * 64 + ((quad * 8) ^ swz));
            a = __builtin_amdgcn_mfma_f32_16x16x32_bf16(kf0, qf0, a, 0, 0, 0);
            sh8 kf1 = *(const sh8*)(kb + (nt * 16 + li) * 64 + ((32 + quad * 8) ^ swz));
            a = __builtin_amdgcn_mfma_f32_16x16x32_bf16(kf1, qf1, a, 0, 0, 0);

            // p = exp(s) (shift cancels in O/l); causal mask on diagonal tile
            ushort4 u;
            float p0, p1, p2, p3;
            if (diag) {
                const int keyb = q0 + nt * 16 + quad * 4;   // j0 == q0 here
                const int qg = qw0 + li;
                p0 = (keyb + 0 > qg) ? 0.f : __expf(a[0]);
                p1 = (keyb + 1 > qg) ? 0.f : __expf(a[1]);
                p2 = (keyb + 2 > qg) ? 0.f : __expf(a[2]);
                p3 = (keyb + 3 > qg) ? 0.f : __expf(a[3]);
            } else {
                p0 = __expf(a[0]); p1 = __expf(a[1]);
                p2 = __expf(a[2]); p3 = __expf(a[3]);
            }
            lacc += (p0 + p1) + (p2 + p3);
            u.x = f2bu(p0); u.y = f2bu(p1); u.z = f2bu(p2); u.w = f2bu(p3);
            // [q=li][key]: 4 consecutive keys -> one b64 write
            *(ushort4*)(&Pl[w][li * PPAD + nt * 16 + quad * 4]) = u;
        }

        // ---- O += P V  (A = P[q=li][key] via ds_read_b128) ----
#pragma unroll
        for (int ks = 0; ks < 2; ++ks) {
            sh8 pf = *(const sh8*)(&Pl[w][li * PPAD + ks * 32 + quad * 8]);
#pragma unroll
            for (int nt = 0; nt < 4; ++nt) {
                sh8 vf = *(const sh8*)(vb + (nt * 16 + li) * 64 +
                                       ((ks * 32 + quad * 8) ^ swz));
                o[nt] = __builtin_amdgcn_mfma_f32_16x16x32_bf16(pf, vf, o[nt], 0, 0, 0);
            }
        }
    }

    // ---- l reduction: sum the 4 quad-lanes sharing this li ----
    lacc += __shfl_xor(lacc, 16, 64);
    lacc += __shfl_xor(lacc, 32, 64);
    // redistribute to C-layout rows: row quad*4+r needs l from lane (quad*4+r)
    float rinv[4];
#pragma unroll
    for (int r = 0; r < 4; ++r)
        rinv[r] = 1.0f / __shfl(lacc, quad * 4 + r, 64);

    const int b = bh >> 4, h = bh & 15;
#pragma unroll
    for (int nt = 0; nt < 4; ++nt)
#pragma unroll
        for (int r = 0; r < 4; ++r) {
            const int q = qw0 + quad * 4 + r;
            Y[((size_t)(b * TT + q)) * EE + h * HD + nt * 16 + li] =
                f2b(o[nt][r] * rinv[r]);
        }
}

// ---------------------------------------------------------------------------
extern "C" void kernel_launch(void* const* d_in, const int* in_sizes, int n_in,
                              void* d_out, int out_size, void* d_ws, size_t ws_size,
                              hipStream_t stream) {
    const float* x      = (const float*)d_in[0];
    const float* w_qkv  = (const float*)d_in[1];
    const float* b_qkv  = (const float*)d_in[2];
    const float* w_proj = (const float*)d_in[3];
    const float* b_proj = (const float*)d_in[4];
    float* out = (float*)d_out;

    const size_t SZ = (size_t)M_ROWS * EE;
    bf16* Q   = (bf16*)d_ws;
    bf16* K   = Q + SZ;
    bf16* V   = K + SZ;
    bf16* XB  = V + SZ;            // x cast; later reused as Y
    bf16* WQT = XB + SZ;           // [3072,1024]
    bf16* WPT = WQT + 3 * SZ / 4;  // [1024,1024]
    bf16* Y   = XB;                // alias: XB dead after gemm_qkv

    // merged prep: 4096 cast blocks + 768 wqkv-transpose + 256 wproj-transpose
    prep<<<dim3(4096 + 768 + 256), dim3(256), 0, stream>>>(
        x, XB, w_qkv, WQT, w_proj, WPT);

    gemm_qkv_mfma<<<dim3(24, 32), dim3(256), 0, stream>>>(XB, WQT, b_qkv, Q, K, V);

    attn_mfma<<<dim3((TT / 64) * (BB * NH)), dim3(256), 0, stream>>>(Q, K, V, Y);

    gemm_proj_mfma<<<dim3(8, 32), dim3(256), 0, stream>>>(Y, WPT, b_proj, out);
}